// Round 13
// baseline (141.044 us; speedup 1.0000x reference)
//
#include <hip/hip_runtime.h>

typedef unsigned int u32;
typedef unsigned long long u64;

#define N_IMG 32
#define NA 67200
#define KTOP 1024
#define IM_F 1280.0f
#define HBIN 4096        // 12-bit radix of u>>18 (u <= 0x3F800000 -> bin <= 4064)
#define HBLK 8           // private-histogram slabs per image
#define NCHK 8           // compact blocks per image
#define CHUNK 8400       // NA / NCHK
#define BCAP 6144        // boundary cap per image (expected ~300-700)
#define BCAP_BLK 2048    // boundary cap per block

// Correctly-rounded f32 exp via double — matches the reference bit-for-bit
// (absmax has been exactly 0.0 since round 1; do not change this chain).
__device__ __forceinline__ float cr_expf(float x) { return (float)exp((double)x); }

__device__ __forceinline__ u64 shflxor64(u64 v, int m) {
    u32 lo = (u32)__shfl_xor((int)(u32)v, m, 64);
    u32 hi = (u32)__shfl_xor((int)(u32)(v >> 32), m, 64);
    return ((u64)hi << 32) | (u64)lo;
}

__device__ __forceinline__ u64 readlane64(u64 v, int lane) {
    u32 lo = (u32)__builtin_amdgcn_readlane((int)(u32)v, lane);
    u32 hi = (u32)__builtin_amdgcn_readlane((int)(u32)(v >> 32), lane);
    return ((u64)hi << 32) | (u64)lo;
}

// ---------------- K1: fused softmax score + private per-slab histogram --------
__global__ __launch_bounds__(256) void score_hist_kernel(const float4* __restrict__ conf4,
                                                         float2* __restrict__ scores2,
                                                         u32* __restrict__ hist,
                                                         u32* __restrict__ gcnt) {
    const int n   = blockIdx.x >> 3;
    const int blk = blockIdx.x & 7;
    const int tid = threadIdx.x;
    if (blockIdx.x == 0) {
        for (int i = tid; i < N_IMG * 16 * 2; i += 256) gcnt[i] = 0;
    }
    __shared__ u32 h[HBIN];
    for (int i = tid; i < HBIN; i += 256) h[i] = 0;
    __syncthreads();
    const int base2 = (n * NA + blk * CHUNK) >> 1;      // float4 index base (CHUNK even)
    #pragma unroll 1
    for (int it = 0; it < 17; ++it) {
        const int idx = tid + it * 256;
        if (idx < CHUNK / 2) {
            float4 c = conf4[base2 + idx];
            float m0  = fmaxf(c.x, c.y);
            float e00 = cr_expf(c.x - m0);
            float e01 = cr_expf(c.y - m0);
            float s0  = e01 / (e00 + e01);
            float m1  = fmaxf(c.z, c.w);
            float e10 = cr_expf(c.z - m1);
            float e11 = cr_expf(c.w - m1);
            float s1  = e11 / (e10 + e11);
            scores2[base2 + idx] = make_float2(s0, s1);
            atomicAdd(&h[__float_as_uint(s0) >> 18], 1u);
            atomicAdd(&h[__float_as_uint(s1) >> 18], 1u);
        }
    }
    __syncthreads();
    u32* out = hist + ((size_t)n * HBLK + blk) * HBIN;
    for (int i = tid; i < HBIN; i += 256) out[i] = h[i];
}

// ---------------- K2: fused thresh + full-chip compact -----------------------
__global__ __launch_bounds__(256) void compact_kernel(const float* __restrict__ scores,
                                                      const u32* __restrict__ hist,
                                                      u64* __restrict__ candd,
                                                      u64* __restrict__ candb,
                                                      u32* __restrict__ gcntd,
                                                      u32* __restrict__ gcntb) {
    const int n   = blockIdx.x >> 3;
    const int blk = blockIdx.x & 7;
    const int tid = threadIdx.x;
    __shared__ u32 binsum[HBIN];         // 16 KB
    __shared__ u32 segA[256], segB[256];
    __shared__ u32 res_b;
    __shared__ u64 dkeys[KTOP];          // 8 KB
    __shared__ u64 bkeys_l[BCAP_BLK];    // 16 KB
    __shared__ u32 cd, cb, based, baseb;
    if (tid == 0) { cd = 0; cb = 0; }

    // --- slab sum ---
    const u32* hb = hist + (size_t)n * HBLK * HBIN;
    #pragma unroll
    for (int g = tid; g < HBIN / 4; g += 256) {
        u32 b0 = 0, b1 = 0, b2 = 0, b3 = 0;
        #pragma unroll
        for (int s = 0; s < HBLK; ++s) {
            const uint4 p = *(const uint4*)(hb + s * HBIN + g * 4);
            b0 += p.x; b1 += p.y; b2 += p.z; b3 += p.w;
        }
        binsum[4 * g]     = b0;
        binsum[4 * g + 1] = b1;
        binsum[4 * g + 2] = b2;
        binsum[4 * g + 3] = b3;
    }
    __syncthreads();

    // --- crossing bin: thread t owns bins [16t, 16t+16) ---
    u32 loc[16];
    #pragma unroll
    for (int i = 0; i < 16; ++i) loc[i] = binsum[16 * tid + i];
    u32 suf[17];                      // suf[i] = sum of loc[i..15]
    suf[16] = 0;
    #pragma unroll
    for (int i = 15; i >= 0; --i) suf[i] = suf[i + 1] + loc[i];
    segA[tid] = suf[0];
    __syncthreads();
    u32 *src = segA, *dst = segB;
    for (int d = 1; d < 256; d <<= 1) {
        dst[tid] = src[tid] + ((tid + d < 256) ? src[tid + d] : 0u);
        __syncthreads();
        u32* t = src; src = dst; dst = t;
    }
    const u32 segNext = (tid + 1 < 256) ? src[tid + 1] : 0u;   // sum of bins >= 16(tid+1)
    #pragma unroll
    for (int i = 0; i < 16; ++i) {
        u32 GE = segNext + suf[i];
        u32 GT = segNext + suf[i + 1];
        if (GE >= KTOP && GT < KTOP) res_b = (u32)(16 * tid + i);   // unique crossing
    }
    __syncthreads();
    const u32 B = res_b;

    // --- chunk scan + compact ---
    const float4* s4 = (const float4*)(scores + (size_t)n * NA + blk * CHUNK);  // 2100 float4
    #pragma unroll 1
    for (int it = 0; it < 9; ++it) {
        const int idx = tid + it * 256;
        if (idx < CHUNK / 4) {
            float4 f = s4[idx];
            const float fe[4] = { f.x, f.y, f.z, f.w };
            #pragma unroll
            for (int e = 0; e < 4; ++e) {
                u32 u = __float_as_uint(fe[e]);
                u32 bin = u >> 18;
                if (bin >= B) {                        // rare (~1.6%)
                    u32 a = (u32)(blk * CHUNK + idx * 4 + e);   // within-image anchor
                    u64 key = ((u64)u << 32) | (u32)(~a);
                    if (bin > B) {
                        u32 p = atomicAdd(&cd, 1u);
                        dkeys[p] = key;
                    } else {
                        u32 p = atomicAdd(&cb, 1u);
                        if (p < BCAP_BLK) bkeys_l[p] = key;
                    }
                }
            }
        }
    }
    __syncthreads();
    const u32 cdl = cd, cbl = min(cb, (u32)BCAP_BLK);
    if (tid == 0) based = atomicAdd(&gcntd[n * 16], cdl);
    if (tid == 1) baseb = atomicAdd(&gcntb[n * 16], cbl);
    __syncthreads();
    for (u32 i = tid; i < cdl; i += 256) candd[(size_t)n * KTOP + based + i] = dkeys[i];
    for (u32 i = tid; i < cbl; i += 256) {
        u32 p = baseb + i;
        if (p < BCAP) candb[(size_t)n * BCAP + p] = bkeys_l[i];
    }
}

// ---------------- K3: exact select + register bitonic (NO gathers) ------------
// key = (score_bits<<32)|~idx ; desc key == score desc, index asc (lax.top_k ties).
__global__ __launch_bounds__(1024) void select_sort_kernel(const u64* __restrict__ candd,
                                                           const u64* __restrict__ candb,
                                                           const u32* __restrict__ gcntd,
                                                           const u32* __restrict__ gcntb,
                                                           u32* __restrict__ top_idx,
                                                           float* __restrict__ top_score) {
    const int n = blockIdx.x, tid = threadIdx.x;
    __shared__ u64 cand[KTOP];      // 8 KB
    __shared__ u64 bk[BCAP];        // 48 KB

    const int D = (int)gcntd[n * 16];              // == GT(B) < KTOP
    const int R = KTOP - D;                        // take R largest boundary keys
    const int E = min((int)gcntb[n * 16], BCAP);   // >= R (GE(B) >= KTOP)
    if (tid < D) cand[tid] = candd[(size_t)n * KTOP + tid];
    for (int t = tid; t < E; t += 1024) bk[t] = candb[(size_t)n * BCAP + t];
    __syncthreads();
    for (int t = tid; t < E; t += 1024) {
        u64 k = bk[t];
        int rank = 0;
        for (int j = 0; j < E; ++j) rank += (bk[j] > k);   // keys unique (idx distinct)
        if (rank < R) cand[D + rank] = k;
    }
    __syncthreads();

    // register bitonic sort, descending, 1024 elements
    u64 v = cand[tid];
    #pragma unroll
    for (int kk = 1; kk <= 10; ++kk) {
        const int k = 1 << kk;
        #pragma unroll
        for (int jj = kk - 1; jj >= 0; --jj) {
            const int j = 1 << jj;
            u64 p;
            if (j >= 64) {
                cand[tid] = v;
                __syncthreads();
                p = cand[tid ^ j];
                __syncthreads();
            } else {
                p = shflxor64(v, j);
            }
            bool keep_max = (((tid & k) == 0) == ((tid & j) == 0));
            u64 mx = v > p ? v : p;
            u64 mn = v > p ? p : v;
            v = keep_max ? mx : mn;
        }
    }

    top_idx[n * KTOP + tid]   = ~(u32)(v & 0xFFFFFFFFull);
    top_score[n * KTOP + tid] = __uint_as_float((u32)(v >> 32));
}

// ---------------- K4: wide decode + det write + IoU mask ----------------------
// 4 blocks/image. Box gathers (2 x float4) are 4x redundant but fully
// latency-hidden at 128 blocks x 16 waves; the 40B landms gather is 1x (sub 0).
__global__ __launch_bounds__(1024) void decode_mask_kernel(const u32* __restrict__ top_idx,
                                                           const float* __restrict__ top_score,
                                                           const float* __restrict__ loc,
                                                           const float* __restrict__ landms,
                                                           const float* __restrict__ priors,
                                                           float* __restrict__ det,
                                                           u64* __restrict__ mask) {
    const int n = blockIdx.x >> 2, sub = blockIdx.x & 3;
    const int tid = threadIdx.x;
    __shared__ float bx1[KTOP], by1[KTOP], bx2[KTOP], by2[KTOP], baA[KTOP];   // 20 KB

    const u32 a = top_idx[n * KTOP + tid];
    float4 p = *(const float4*)(priors + (size_t)a * 4);
    float4 l = *(const float4*)(loc + ((size_t)n * NA + a) * 4);
    float cx = p.x + l.x * 0.1f * p.z;
    float cy = p.y + l.y * 0.1f * p.w;
    float w  = p.z * cr_expf(l.z * 0.2f);
    float h  = p.w * cr_expf(l.w * 0.2f);
    const float o0 = (cx - w * 0.5f) * IM_F;
    const float o1 = (cy - h * 0.5f) * IM_F;
    const float o2 = (cx + w * 0.5f) * IM_F;
    const float o3 = (cy + h * 0.5f) * IM_F;

    bx1[tid] = o0; by1[tid] = o1; bx2[tid] = o2; by2[tid] = o3;
    baA[tid] = fmaxf(o2 - o0, 0.f) * fmaxf(o3 - o1, 0.f);

    if (sub == 0) {
        float* o = det + ((size_t)n * KTOP + tid) * 15;
        o[0] = o0; o[1] = o1; o[2] = o2; o[3] = o3;
        o[4] = top_score[n * KTOP + tid];
        const float* mp = landms + ((size_t)n * NA + a) * 10;
        #pragma unroll
        for (int q = 0; q < 5; ++q) {
            o[5 + 2 * q]     = (p.x + mp[2 * q]     * 0.1f * p.z) * IM_F;
            o[5 + 2 * q + 1] = (p.y + mp[2 * q + 1] * 0.1f * p.w) * IM_F;
        }
    }
    __syncthreads();

    // mask quarter: wave q = sub*16 + wid handles rows i === q (mod 64)
    const int wid  = tid >> 6;
    const int lane = tid & 63;
    const int q    = sub * 16 + wid;
    u64* mbase = mask + (size_t)n * KTOP * 16;
    #pragma unroll 1
    for (int k = 0; k < 16; ++k) {
        const int i = k * 64 + q;
        const float x1i = bx1[i], y1i = by1[i], x2i = bx2[i], y2i = by2[i], ai = baA[i];
        u64* orow = mbase + (size_t)i * 16;
        if (lane < k) orow[lane] = 0ull;               // zero low words
        #pragma unroll 1
        for (int w2 = k; w2 < 16; ++w2) {
            const int j = w2 * 64 + lane;
            bool bit = false;
            if (j > i) {
                float xx1 = fmaxf(x1i, bx1[j]);
                float yy1 = fmaxf(y1i, by1[j]);
                float xx2 = fminf(x2i, bx2[j]);
                float yy2 = fminf(y2i, by2[j]);
                float inter = fmaxf(xx2 - xx1, 0.f) * fmaxf(yy2 - yy1, 0.f);
                float iou = inter / (ai + baA[j] - inter + 1e-9f);   // ref formula order
                bit = iou > 0.4f;
            }
            u64 m = __ballot(bit);
            if (lane == 0) orow[w2] = m;
        }
    }
}

// ---------------- K5: group-structured greedy NMS + fused masked output -------
__global__ __launch_bounds__(1024) void nms_out_kernel(const float* __restrict__ top_score,
                                                       const u64* __restrict__ mask,
                                                       const float* __restrict__ det,
                                                       float* __restrict__ out) {
    const int n = blockIdx.x;
    const int tid = threadIdx.x;
    __shared__ u64 lmask[512 * 16];   // 64 KB: one half (512 rows x 16 words), swizzled

    const u64* mbase = mask + (size_t)n * KTOP * 16;
    u64 myw = 0;                      // lane w (0..15) holds keep word w
    if (tid < 64) {
        for (int g = 0; g < 16; ++g) {
            u64 b = __ballot(top_score[n * KTOP + g * 64 + tid] > 0.5f);
            if (tid == g) myw = b;
        }
    }

    const int lane = tid & 63;
    const int w16  = lane & 15;
    const int p4   = lane >> 4;       // 0..3 (for tid<64)

    #pragma unroll 1
    for (int half = 0; half < 2; ++half) {
        __syncthreads();   // protect lmask from previous half's readers
        #pragma unroll
        for (int k = 0; k < 8; ++k) {
            int idx = tid + k * 1024;          // linear u64 index within half
            int r = idx >> 4, w = idx & 15;
            lmask[(r << 4) | (w ^ (r & 15))] = mbase[(size_t)half * 8192 + idx];
        }
        __syncthreads();
        if (tid < 64) {
            #pragma unroll 1
            for (int gg = 0; gg < 8; ++gg) {
                const int g = half * 8 + gg;
                const int lbase = gg * 64;                   // local row base
                const int rr = lbase + lane;
                u64 colw = lmask[(rr << 4) | (g ^ (rr & 15))];
                u64 kw = readlane64(myw, g);
                #pragma unroll
                for (int l = 0; l < 64; ++l) {               // pure-register serial chain
                    u64 rl = readlane64(colw, l);
                    kw = ((kw >> l) & 1ull) ? (kw & ~rl) : kw;
                }
                u64 acc = 0;                                  // branchless suppression
                #pragma unroll
                for (int k = 0; k < 16; ++k) {
                    const int r2 = lbase + p4 * 16 + k;
                    u64 row = lmask[(r2 << 4) | (w16 ^ (r2 & 15))];
                    u64 sel = (u64)0 - ((kw >> (p4 * 16 + k)) & 1ull);
                    acc |= row & sel;
                }
                acc |= shflxor64(acc, 16);
                acc |= shflxor64(acc, 32);   // lanes 0..15: full suppress word w16
                myw = (lane == g) ? kw : myw;
                myw &= ~acc;                 // idempotent for word g
            }
        }
    }
    __syncthreads();
    if (tid < 16) lmask[tid] = myw;   // publish keep bits (mask rows no longer needed)
    __syncthreads();

    // masked output write: 15360 floats per image, element-parallel (coalesced)
    const float* drow = det + (size_t)n * KTOP * 15;
    float* orow = out + (size_t)n * KTOP * 15;
    for (int e = tid; e < KTOP * 15; e += 1024) {
        int k = e / 15;
        float f = ((lmask[k >> 6] >> (k & 63)) & 1ull) ? 1.0f : 0.0f;
        orow[e] = drow[e] * f;
    }
}

extern "C" void kernel_launch(void* const* d_in, const int* in_sizes, int n_in,
                              void* d_out, int out_size, void* d_ws, size_t ws_size,
                              hipStream_t stream) {
    const float* loc    = (const float*)d_in[0];
    const float* conf   = (const float*)d_in[1];
    const float* landms = (const float*)d_in[2];
    const float* priors = (const float*)d_in[3];

    char* ws = (char*)d_ws;
    size_t off = 0;
    auto carve = [&](size_t bytes) { void* p = ws + off; off = (off + bytes + 255) & ~255ull; return p; };
    float* scores    = (float*)carve(sizeof(float) * (size_t)N_IMG * NA);
    u32*   top_idx   = (u32*)  carve(sizeof(u32)   * N_IMG * KTOP);
    float* top_score = (float*)carve(sizeof(float) * N_IMG * KTOP);
    float* det       = (float*)carve(sizeof(float) * N_IMG * KTOP * 15);
    u32*   hist      = (u32*)  carve(sizeof(u32)   * (size_t)N_IMG * HBLK * HBIN); // 4 MB
    u64*   mask      = (u64*)  carve(sizeof(u64)   * (size_t)N_IMG * KTOP * 16);   // 4 MB
    u64*   candd     = (u64*)  carve(sizeof(u64)   * (size_t)N_IMG * KTOP);        // 256 KB
    u64*   candb     = (u64*)  carve(sizeof(u64)   * (size_t)N_IMG * BCAP);        // 1.5 MB
    u32*   gcnt      = (u32*)  carve(sizeof(u32)   * N_IMG * 16 * 2);              // 64B-padded counters
    u32*   gcntd = gcnt, *gcntb = gcnt + N_IMG * 16;

    score_hist_kernel<<<N_IMG * NCHK, 256, 0, stream>>>((const float4*)conf, (float2*)scores,
                                                        hist, gcnt);
    compact_kernel<<<N_IMG * NCHK, 256, 0, stream>>>(scores, hist, candd, candb, gcntd, gcntb);
    select_sort_kernel<<<N_IMG, 1024, 0, stream>>>(candd, candb, gcntd, gcntb, top_idx, top_score);
    decode_mask_kernel<<<N_IMG * 4, 1024, 0, stream>>>(top_idx, top_score, loc, landms, priors,
                                                       det, mask);
    nms_out_kernel<<<N_IMG, 1024, 0, stream>>>(top_score, mask, det, (float*)d_out);
}

// Round 14
// 129.088 us; speedup vs baseline: 1.0926x; 1.0926x over previous
//
#include <hip/hip_runtime.h>

typedef unsigned int u32;
typedef unsigned long long u64;

#define N_IMG 32
#define NA 67200
#define KTOP 1024
#define IM_F 1280.0f
#define HBIN 4096        // 12-bit radix of u>>18 (u <= 0x3F800000 -> bin <= 4064)
#define HBLK 8           // private-histogram slabs per image
#define NCHK 8           // compact blocks per image
#define CHUNK 8400       // NA / NCHK
#define BCAP 6144        // boundary cap per image (expected ~300-700)
#define BCAP_BLK 2048    // boundary cap per block

// Correctly-rounded f32 exp via double — matches the reference bit-for-bit
// (absmax has been exactly 0.0 since round 1; do not change this chain).
__device__ __forceinline__ float cr_expf(float x) { return (float)exp((double)x); }

__device__ __forceinline__ u64 shflxor64(u64 v, int m) {
    u32 lo = (u32)__shfl_xor((int)(u32)v, m, 64);
    u32 hi = (u32)__shfl_xor((int)(u32)(v >> 32), m, 64);
    return ((u64)hi << 32) | (u64)lo;
}

__device__ __forceinline__ u64 readlane64(u64 v, int lane) {
    u32 lo = (u32)__builtin_amdgcn_readlane((int)(u32)v, lane);
    u32 hi = (u32)__builtin_amdgcn_readlane((int)(u32)(v >> 32), lane);
    return ((u64)hi << 32) | (u64)lo;
}

// ---------------- K1: fused softmax score + private per-slab histogram --------
__global__ __launch_bounds__(256) void score_hist_kernel(const float4* __restrict__ conf4,
                                                         float2* __restrict__ scores2,
                                                         u32* __restrict__ hist,
                                                         u32* __restrict__ gcnt) {
    const int n   = blockIdx.x >> 3;
    const int blk = blockIdx.x & 7;
    const int tid = threadIdx.x;
    if (blockIdx.x == 0) {
        for (int i = tid; i < N_IMG * 16 * 2; i += 256) gcnt[i] = 0;
    }
    __shared__ u32 h[HBIN];
    for (int i = tid; i < HBIN; i += 256) h[i] = 0;
    __syncthreads();
    const int base2 = (n * NA + blk * CHUNK) >> 1;      // float4 index base (CHUNK even)
    #pragma unroll 1
    for (int it = 0; it < 17; ++it) {
        const int idx = tid + it * 256;
        if (idx < CHUNK / 2) {
            float4 c = conf4[base2 + idx];
            float m0  = fmaxf(c.x, c.y);
            float e00 = cr_expf(c.x - m0);
            float e01 = cr_expf(c.y - m0);
            float s0  = e01 / (e00 + e01);
            float m1  = fmaxf(c.z, c.w);
            float e10 = cr_expf(c.z - m1);
            float e11 = cr_expf(c.w - m1);
            float s1  = e11 / (e10 + e11);
            scores2[base2 + idx] = make_float2(s0, s1);
            atomicAdd(&h[__float_as_uint(s0) >> 18], 1u);
            atomicAdd(&h[__float_as_uint(s1) >> 18], 1u);
        }
    }
    __syncthreads();
    u32* out = hist + ((size_t)n * HBLK + blk) * HBIN;
    for (int i = tid; i < HBIN; i += 256) out[i] = h[i];
}

// ---------------- K2: fused thresh + full-chip compact -----------------------
__global__ __launch_bounds__(256) void compact_kernel(const float* __restrict__ scores,
                                                      const u32* __restrict__ hist,
                                                      u64* __restrict__ candd,
                                                      u64* __restrict__ candb,
                                                      u32* __restrict__ gcntd,
                                                      u32* __restrict__ gcntb) {
    const int n   = blockIdx.x >> 3;
    const int blk = blockIdx.x & 7;
    const int tid = threadIdx.x;
    __shared__ u32 binsum[HBIN];         // 16 KB
    __shared__ u32 segA[256], segB[256];
    __shared__ u32 res_b;
    __shared__ u64 dkeys[KTOP];          // 8 KB
    __shared__ u64 bkeys_l[BCAP_BLK];    // 16 KB
    __shared__ u32 cd, cb, based, baseb;
    if (tid == 0) { cd = 0; cb = 0; }

    // --- slab sum ---
    const u32* hb = hist + (size_t)n * HBLK * HBIN;
    #pragma unroll
    for (int g = tid; g < HBIN / 4; g += 256) {
        u32 b0 = 0, b1 = 0, b2 = 0, b3 = 0;
        #pragma unroll
        for (int s = 0; s < HBLK; ++s) {
            const uint4 p = *(const uint4*)(hb + s * HBIN + g * 4);
            b0 += p.x; b1 += p.y; b2 += p.z; b3 += p.w;
        }
        binsum[4 * g]     = b0;
        binsum[4 * g + 1] = b1;
        binsum[4 * g + 2] = b2;
        binsum[4 * g + 3] = b3;
    }
    __syncthreads();

    // --- crossing bin: thread t owns bins [16t, 16t+16) ---
    u32 loc[16];
    #pragma unroll
    for (int i = 0; i < 16; ++i) loc[i] = binsum[16 * tid + i];
    u32 suf[17];                      // suf[i] = sum of loc[i..15]
    suf[16] = 0;
    #pragma unroll
    for (int i = 15; i >= 0; --i) suf[i] = suf[i + 1] + loc[i];
    segA[tid] = suf[0];
    __syncthreads();
    u32 *src = segA, *dst = segB;
    for (int d = 1; d < 256; d <<= 1) {
        dst[tid] = src[tid] + ((tid + d < 256) ? src[tid + d] : 0u);
        __syncthreads();
        u32* t = src; src = dst; dst = t;
    }
    const u32 segNext = (tid + 1 < 256) ? src[tid + 1] : 0u;   // sum of bins >= 16(tid+1)
    #pragma unroll
    for (int i = 0; i < 16; ++i) {
        u32 GE = segNext + suf[i];
        u32 GT = segNext + suf[i + 1];
        if (GE >= KTOP && GT < KTOP) res_b = (u32)(16 * tid + i);   // unique crossing
    }
    __syncthreads();
    const u32 B = res_b;

    // --- chunk scan + compact ---
    const float4* s4 = (const float4*)(scores + (size_t)n * NA + blk * CHUNK);  // 2100 float4
    #pragma unroll 1
    for (int it = 0; it < 9; ++it) {
        const int idx = tid + it * 256;
        if (idx < CHUNK / 4) {
            float4 f = s4[idx];
            const float fe[4] = { f.x, f.y, f.z, f.w };
            #pragma unroll
            for (int e = 0; e < 4; ++e) {
                u32 u = __float_as_uint(fe[e]);
                u32 bin = u >> 18;
                if (bin >= B) {                        // rare (~1.6%)
                    u32 a = (u32)(blk * CHUNK + idx * 4 + e);   // within-image anchor
                    u64 key = ((u64)u << 32) | (u32)(~a);
                    if (bin > B) {
                        u32 p = atomicAdd(&cd, 1u);
                        dkeys[p] = key;
                    } else {
                        u32 p = atomicAdd(&cb, 1u);
                        if (p < BCAP_BLK) bkeys_l[p] = key;
                    }
                }
            }
        }
    }
    __syncthreads();
    const u32 cdl = cd, cbl = min(cb, (u32)BCAP_BLK);
    if (tid == 0) based = atomicAdd(&gcntd[n * 16], cdl);
    if (tid == 1) baseb = atomicAdd(&gcntb[n * 16], cbl);
    __syncthreads();
    for (u32 i = tid; i < cdl; i += 256) candd[(size_t)n * KTOP + based + i] = dkeys[i];
    for (u32 i = tid; i < cbl; i += 256) {
        u32 p = baseb + i;
        if (p < BCAP) candb[(size_t)n * BCAP + p] = bkeys_l[i];
    }
}

// ---------------- K3: exact select + register bitonic (NO gathers) ------------
__global__ __launch_bounds__(1024) void select_sort_kernel(const u64* __restrict__ candd,
                                                           const u64* __restrict__ candb,
                                                           const u32* __restrict__ gcntd,
                                                           const u32* __restrict__ gcntb,
                                                           u32* __restrict__ top_idx,
                                                           float* __restrict__ top_score) {
    const int n = blockIdx.x, tid = threadIdx.x;
    __shared__ u64 cand[KTOP];      // 8 KB
    __shared__ u64 bk[BCAP];        // 48 KB

    const int D = (int)gcntd[n * 16];              // == GT(B) < KTOP
    const int R = KTOP - D;                        // take R largest boundary keys
    const int E = min((int)gcntb[n * 16], BCAP);   // >= R (GE(B) >= KTOP)
    if (tid < D) cand[tid] = candd[(size_t)n * KTOP + tid];
    for (int t = tid; t < E; t += 1024) bk[t] = candb[(size_t)n * BCAP + t];
    __syncthreads();
    for (int t = tid; t < E; t += 1024) {
        u64 k = bk[t];
        int rank = 0;
        for (int j = 0; j < E; ++j) rank += (bk[j] > k);   // keys unique (idx distinct)
        if (rank < R) cand[D + rank] = k;
    }
    __syncthreads();

    // register bitonic sort, descending, 1024 elements
    u64 v = cand[tid];
    #pragma unroll
    for (int kk = 1; kk <= 10; ++kk) {
        const int k = 1 << kk;
        #pragma unroll
        for (int jj = kk - 1; jj >= 0; --jj) {
            const int j = 1 << jj;
            u64 p;
            if (j >= 64) {
                cand[tid] = v;
                __syncthreads();
                p = cand[tid ^ j];
                __syncthreads();
            } else {
                p = shflxor64(v, j);
            }
            bool keep_max = (((tid & k) == 0) == ((tid & j) == 0));
            u64 mx = v > p ? v : p;
            u64 mn = v > p ? p : v;
            v = keep_max ? mx : mn;
        }
    }

    top_idx[n * KTOP + tid]   = ~(u32)(v & 0xFFFFFFFFull);
    top_score[n * KTOP + tid] = __uint_as_float((u32)(v >> 32));
}

// ---------------- K4: wide 1x decode (one rank per thread, no LDS) ------------
// 128 blocks x 256 threads over 256 CUs; 3 independent gathers per thread,
// fully latency-hidden. Writes det rows + box SoA for the mask kernel.
__global__ __launch_bounds__(256) void decode_kernel(const u32* __restrict__ top_idx,
                                                     const float* __restrict__ top_score,
                                                     const float* __restrict__ loc,
                                                     const float* __restrict__ landms,
                                                     const float* __restrict__ priors,
                                                     float* __restrict__ det,
                                                     float* __restrict__ boxes) {
    const int id = blockIdx.x * 256 + threadIdx.x;   // 0 .. 32767
    const int n = id >> 10, r = id & 1023;
    const u32 a = top_idx[id];

    float4 p = *(const float4*)(priors + (size_t)a * 4);
    float4 l = *(const float4*)(loc + ((size_t)n * NA + a) * 4);
    float cx = p.x + l.x * 0.1f * p.z;
    float cy = p.y + l.y * 0.1f * p.w;
    float w  = p.z * cr_expf(l.z * 0.2f);
    float h  = p.w * cr_expf(l.w * 0.2f);
    const float o0 = (cx - w * 0.5f) * IM_F;
    const float o1 = (cy - h * 0.5f) * IM_F;
    const float o2 = (cx + w * 0.5f) * IM_F;
    const float o3 = (cy + h * 0.5f) * IM_F;

    float* o = det + (size_t)id * 15;
    o[0] = o0; o[1] = o1; o[2] = o2; o[3] = o3;
    o[4] = top_score[id];
    const float* mp = landms + ((size_t)n * NA + a) * 10;
    #pragma unroll
    for (int q = 0; q < 5; ++q) {
        o[5 + 2 * q]     = (p.x + mp[2 * q]     * 0.1f * p.z) * IM_F;
        o[5 + 2 * q + 1] = (p.y + mp[2 * q + 1] * 0.1f * p.w) * IM_F;
    }

    float* bb = boxes + (size_t)n * 5 * KTOP;        // SoA: x1,y1,x2,y2,area
    bb[r]            = o0;
    bb[KTOP + r]     = o1;
    bb[2 * KTOP + r] = o2;
    bb[3 * KTOP + r] = o3;
    bb[4 * KTOP + r] = fmaxf(o2 - o0, 0.f) * fmaxf(o3 - o1, 0.f);
}

// ---------------- K5: IoU suppression bitmask, wave-per-row + ballot ----------
// Reads the 20 KB box SoA coalesced (L2-hot), no gathers. 16 blocks/image.
__global__ __launch_bounds__(256) void mask_kernel(const float* __restrict__ boxes,
                                                   u64* __restrict__ mask) {
    const int n    = blockIdx.x >> 4;        // image
    const int sub  = blockIdx.x & 15;        // block within image
    const int wid  = threadIdx.x >> 6;       // wave in block
    const int lane = threadIdx.x & 63;
    const int q    = sub * 4 + wid;          // wave id within image, 0..63
    const int tid  = threadIdx.x;

    __shared__ float bx1[KTOP], by1[KTOP], bx2[KTOP], by2[KTOP], baA[KTOP];
    const float* bb = boxes + (size_t)n * 5 * KTOP;
    for (int j = tid; j < KTOP; j += 256) {
        bx1[j] = bb[j];
        by1[j] = bb[KTOP + j];
        bx2[j] = bb[2 * KTOP + j];
        by2[j] = bb[3 * KTOP + j];
        baA[j] = bb[4 * KTOP + j];
    }
    __syncthreads();

    u64* mbase = mask + (size_t)n * KTOP * 16;
    #pragma unroll 1
    for (int k = 0; k < 16; ++k) {
        const int i = k * 64 + q;
        const float x1i = bx1[i], y1i = by1[i], x2i = bx2[i], y2i = by2[i], ai = baA[i];
        u64* orow = mbase + (size_t)i * 16;
        if (lane < k) orow[lane] = 0ull;               // zero low words
        #pragma unroll 1
        for (int w2 = k; w2 < 16; ++w2) {
            const int j = w2 * 64 + lane;
            bool bit = false;
            if (j > i) {
                float xx1 = fmaxf(x1i, bx1[j]);
                float yy1 = fmaxf(y1i, by1[j]);
                float xx2 = fminf(x2i, bx2[j]);
                float yy2 = fminf(y2i, by2[j]);
                float inter = fmaxf(xx2 - xx1, 0.f) * fmaxf(yy2 - yy1, 0.f);
                float iou = inter / (ai + baA[j] - inter + 1e-9f);   // ref formula order
                bit = iou > 0.4f;
            }
            u64 m = __ballot(bit);
            if (lane == 0) orow[w2] = m;
        }
    }
}

// ---------------- K6: group-structured greedy NMS + fused masked output -------
__global__ __launch_bounds__(1024) void nms_out_kernel(const float* __restrict__ top_score,
                                                       const u64* __restrict__ mask,
                                                       const float* __restrict__ det,
                                                       float* __restrict__ out) {
    const int n = blockIdx.x;
    const int tid = threadIdx.x;
    __shared__ u64 lmask[512 * 16];   // 64 KB: one half (512 rows x 16 words), swizzled

    const u64* mbase = mask + (size_t)n * KTOP * 16;
    u64 myw = 0;                      // lane w (0..15) holds keep word w
    if (tid < 64) {
        for (int g = 0; g < 16; ++g) {
            u64 b = __ballot(top_score[n * KTOP + g * 64 + tid] > 0.5f);
            if (tid == g) myw = b;
        }
    }

    const int lane = tid & 63;
    const int w16  = lane & 15;
    const int p4   = lane >> 4;       // 0..3 (for tid<64)

    #pragma unroll 1
    for (int half = 0; half < 2; ++half) {
        __syncthreads();   // protect lmask from previous half's readers
        #pragma unroll
        for (int k = 0; k < 8; ++k) {
            int idx = tid + k * 1024;          // linear u64 index within half
            int r = idx >> 4, w = idx & 15;
            lmask[(r << 4) | (w ^ (r & 15))] = mbase[(size_t)half * 8192 + idx];
        }
        __syncthreads();
        if (tid < 64) {
            #pragma unroll 1
            for (int gg = 0; gg < 8; ++gg) {
                const int g = half * 8 + gg;
                const int lbase = gg * 64;                   // local row base
                const int rr = lbase + lane;
                u64 colw = lmask[(rr << 4) | (g ^ (rr & 15))];
                u64 kw = readlane64(myw, g);
                #pragma unroll
                for (int l = 0; l < 64; ++l) {               // pure-register serial chain
                    u64 rl = readlane64(colw, l);
                    kw = ((kw >> l) & 1ull) ? (kw & ~rl) : kw;
                }
                u64 acc = 0;                                  // branchless suppression
                #pragma unroll
                for (int k = 0; k < 16; ++k) {
                    const int r2 = lbase + p4 * 16 + k;
                    u64 row = lmask[(r2 << 4) | (w16 ^ (r2 & 15))];
                    u64 sel = (u64)0 - ((kw >> (p4 * 16 + k)) & 1ull);
                    acc |= row & sel;
                }
                acc |= shflxor64(acc, 16);
                acc |= shflxor64(acc, 32);   // lanes 0..15: full suppress word w16
                myw = (lane == g) ? kw : myw;
                myw &= ~acc;                 // idempotent for word g
            }
        }
    }
    __syncthreads();
    if (tid < 16) lmask[tid] = myw;   // publish keep bits (mask rows no longer needed)
    __syncthreads();

    // masked output write: 15360 floats per image, element-parallel (coalesced)
    const float* drow = det + (size_t)n * KTOP * 15;
    float* orow = out + (size_t)n * KTOP * 15;
    for (int e = tid; e < KTOP * 15; e += 1024) {
        int k = e / 15;
        float f = ((lmask[k >> 6] >> (k & 63)) & 1ull) ? 1.0f : 0.0f;
        orow[e] = drow[e] * f;
    }
}

extern "C" void kernel_launch(void* const* d_in, const int* in_sizes, int n_in,
                              void* d_out, int out_size, void* d_ws, size_t ws_size,
                              hipStream_t stream) {
    const float* loc    = (const float*)d_in[0];
    const float* conf   = (const float*)d_in[1];
    const float* landms = (const float*)d_in[2];
    const float* priors = (const float*)d_in[3];

    char* ws = (char*)d_ws;
    size_t off = 0;
    auto carve = [&](size_t bytes) { void* p = ws + off; off = (off + bytes + 255) & ~255ull; return p; };
    float* scores    = (float*)carve(sizeof(float) * (size_t)N_IMG * NA);
    u32*   top_idx   = (u32*)  carve(sizeof(u32)   * N_IMG * KTOP);
    float* top_score = (float*)carve(sizeof(float) * N_IMG * KTOP);
    float* det       = (float*)carve(sizeof(float) * N_IMG * KTOP * 15);
    float* boxes     = (float*)carve(sizeof(float) * N_IMG * 5 * KTOP);            // 640 KB SoA
    u32*   hist      = (u32*)  carve(sizeof(u32)   * (size_t)N_IMG * HBLK * HBIN); // 4 MB
    u64*   mask      = (u64*)  carve(sizeof(u64)   * (size_t)N_IMG * KTOP * 16);   // 4 MB
    u64*   candd     = (u64*)  carve(sizeof(u64)   * (size_t)N_IMG * KTOP);        // 256 KB
    u64*   candb     = (u64*)  carve(sizeof(u64)   * (size_t)N_IMG * BCAP);        // 1.5 MB
    u32*   gcnt      = (u32*)  carve(sizeof(u32)   * N_IMG * 16 * 2);              // 64B-padded counters
    u32*   gcntd = gcnt, *gcntb = gcnt + N_IMG * 16;

    score_hist_kernel<<<N_IMG * NCHK, 256, 0, stream>>>((const float4*)conf, (float2*)scores,
                                                        hist, gcnt);
    compact_kernel<<<N_IMG * NCHK, 256, 0, stream>>>(scores, hist, candd, candb, gcntd, gcntb);
    select_sort_kernel<<<N_IMG, 1024, 0, stream>>>(candd, candb, gcntd, gcntb, top_idx, top_score);
    decode_kernel<<<N_IMG * KTOP / 256, 256, 0, stream>>>(top_idx, top_score, loc, landms, priors,
                                                          det, boxes);
    mask_kernel<<<N_IMG * 16, 256, 0, stream>>>(boxes, mask);
    nms_out_kernel<<<N_IMG, 1024, 0, stream>>>(top_score, mask, det, (float*)d_out);
}